// Round 2
// baseline (3731.111 us; speedup 1.0000x reference)
//
#include <hip/hip_runtime.h>
#include <hip/hip_bf16.h>

typedef unsigned short u16;
typedef short bf16x8 __attribute__((ext_vector_type(8)));
typedef float f32x4 __attribute__((ext_vector_type(4)));

#define BM 64
#define BN 64
#define BK 32
#define ADJ_LD 66

__device__ __forceinline__ float bf2f(u16 u) {
    union { unsigned int i; float f; } x;
    x.i = ((unsigned int)u) << 16;
    return x.f;
}
__device__ __forceinline__ u16 f2bf(float f) {
    union { float f; unsigned int i; } x;
    x.f = f;
    unsigned int i = x.i;
    i += 0x7fffu + ((i >> 16) & 1u);  // RNE
    return (u16)(i >> 16);
}

// C[m, c_off+n] = relu( A[m, a_off+k] @ (W[n,k] * adj[k,n]) + bias[n] )
// A is f32 (a_f32=1) or bf16-in-ws (a_f32=0); W/adj/bias f32; C bf16.
__global__ __launch_bounds__(256) void masked_gemm_kernel(
    const void* __restrict__ Av, int lda, int a_off, int a_f32,
    const float* __restrict__ W,      // N x K row-major f32
    const float* __restrict__ adj,    // K x N row-major f32 (nullable)
    const float* __restrict__ bias,   // N f32
    u16* __restrict__ C, int ldc, int c_off,
    int N, int K)
{
    __shared__ __align__(16) u16 As[BM * BK];
    __shared__ __align__(16) u16 Bs[BN * BK];
    __shared__ __align__(16) u16 adjS[BK * ADJ_LD];

    const int t  = threadIdx.x;
    const int m0 = blockIdx.y * BM;
    const int n0 = blockIdx.x * BN;

    const int am = t >> 2;            // 0..63
    const int ak = (t & 3) * 8;       // 0,8,16,24
    const bool wvalid = (n0 + am) < N;
    const int jk = t >> 3;            // 0..31
    const int jn = (t & 7) * 8;       // 0..56

    const int lane  = t & 63;
    const int wave  = t >> 6;
    const int wm    = (wave >> 1) * 32;
    const int wnoff = (wave & 1) * 32;
    const int fr    = lane & 15;
    const int fq    = lane >> 4;
    const int kq    = fq * 8;

    const float* Af = (const float*)Av + (size_t)(m0 + am) * lda + a_off;
    const u16*   Ah = (const u16*)Av + (size_t)(m0 + am) * lda + a_off;
    const float* Wrow = W + (size_t)(n0 + am) * K;

    f32x4 acc[2][2] = {};

    const int nk = (K + BK - 1) / BK;
    for (int kt = 0; kt < nk; ++kt) {
        const int k0 = kt * BK;
        __syncthreads();
        // ---- stage A (64x32) ----
        {
            const int kg = k0 + ak;
            u16* dst = &As[am * BK + ak];
            if (a_f32) {
                if (kg + 8 <= K) {
                    float4 u0 = *(const float4*)&Af[kg];
                    float4 u1 = *(const float4*)&Af[kg + 4];
                    u16 tmp[8] = { f2bf(u0.x), f2bf(u0.y), f2bf(u0.z), f2bf(u0.w),
                                   f2bf(u1.x), f2bf(u1.y), f2bf(u1.z), f2bf(u1.w) };
                    *(uint4*)dst = *(const uint4*)tmp;
                } else {
                    #pragma unroll
                    for (int j = 0; j < 8; ++j)
                        dst[j] = (kg + j < K) ? f2bf(Af[kg + j]) : (u16)0;
                }
            } else {
                if (kg + 8 <= K) {
                    *(uint4*)dst = *(const uint4*)&Ah[kg];
                } else {
                    #pragma unroll
                    for (int j = 0; j < 8; ++j)
                        dst[j] = (kg + j < K) ? Ah[kg + j] : (u16)0;
                }
            }
        }
        // ---- stage W (64x32, n-major) ----
        {
            const int kg = k0 + ak;
            u16* dst = &Bs[am * BK + ak];
            if (wvalid && kg + 8 <= K) {
                float4 u0 = *(const float4*)&Wrow[kg];
                float4 u1 = *(const float4*)&Wrow[kg + 4];
                u16 tmp[8] = { f2bf(u0.x), f2bf(u0.y), f2bf(u0.z), f2bf(u0.w),
                               f2bf(u1.x), f2bf(u1.y), f2bf(u1.z), f2bf(u1.w) };
                *(uint4*)dst = *(const uint4*)tmp;
            } else {
                #pragma unroll
                for (int j = 0; j < 8; ++j)
                    dst[j] = (wvalid && kg + j < K) ? f2bf(Wrow[kg + j]) : (u16)0;
            }
        }
        // ---- stage adj (32x64 k-major, as 0/1 flags) + mask Bs ----
        if (adj) {
            const int kg = k0 + jk;
            u16* dst = &adjS[jk * ADJ_LD + jn];
            if (kg < K && n0 + jn + 8 <= N) {
                const float* ap = &adj[(size_t)kg * N + n0 + jn];
                float4 u0 = *(const float4*)&ap[0];
                float4 u1 = *(const float4*)&ap[4];
                u16 tmp[8] = { (u16)(u0.x != 0.f), (u16)(u0.y != 0.f),
                               (u16)(u0.z != 0.f), (u16)(u0.w != 0.f),
                               (u16)(u1.x != 0.f), (u16)(u1.y != 0.f),
                               (u16)(u1.z != 0.f), (u16)(u1.w != 0.f) };
                *(uint4*)dst = *(const uint4*)tmp;
            } else {
                #pragma unroll
                for (int j = 0; j < 8; ++j)
                    dst[j] = (kg < K && n0 + jn + j < N)
                                 ? (u16)(adj[(size_t)kg * N + n0 + jn + j] != 0.f) : (u16)0;
            }
            __syncthreads();
            #pragma unroll
            for (int j = 0; j < 8; ++j) {
                if (adjS[(ak + j) * ADJ_LD + am] == 0)
                    Bs[am * BK + ak + j] = 0;
            }
        }
        __syncthreads();

        // ---- MFMA: 2x2 of 16x16x32 per wave ----
        bf16x8 a0 = *(const bf16x8*)&As[(wm + fr) * BK + kq];
        bf16x8 a1 = *(const bf16x8*)&As[(wm + 16 + fr) * BK + kq];
        bf16x8 b0 = *(const bf16x8*)&Bs[(wnoff + fr) * BK + kq];
        bf16x8 b1 = *(const bf16x8*)&Bs[(wnoff + 16 + fr) * BK + kq];
        acc[0][0] = __builtin_amdgcn_mfma_f32_16x16x32_bf16(a0, b0, acc[0][0], 0, 0, 0);
        acc[0][1] = __builtin_amdgcn_mfma_f32_16x16x32_bf16(a0, b1, acc[0][1], 0, 0, 0);
        acc[1][0] = __builtin_amdgcn_mfma_f32_16x16x32_bf16(a1, b0, acc[1][0], 0, 0, 0);
        acc[1][1] = __builtin_amdgcn_mfma_f32_16x16x32_bf16(a1, b1, acc[1][1], 0, 0, 0);
    }

    // ---- epilogue: bias + relu + bf16 store ----
    #pragma unroll
    for (int tn = 0; tn < 2; ++tn) {
        const int gcol = n0 + wnoff + tn * 16 + fr;
        if (gcol >= N) continue;
        const float bv = bias[gcol];
        #pragma unroll
        for (int tm = 0; tm < 2; ++tm) {
            #pragma unroll
            for (int r = 0; r < 4; ++r) {
                const int grow = m0 + wm + tm * 16 + fq * 4 + r;
                float v = acc[tm][tn][r] + bv;
                v = v > 0.f ? v : 0.f;
                C[(size_t)grow * ldc + c_off + gcol] = f2bf(v);
            }
        }
    }
}

// y = sigmoid(h2 @ W_out.T + b_out); h2 bf16 512x256, Wout/bout f32, out f32
__global__ __launch_bounds__(64) void final_kernel(
    const u16* __restrict__ h2, const float* __restrict__ Wout,
    const float* __restrict__ bout, float* __restrict__ out)
{
    const int r = blockIdx.x;
    const int lane = threadIdx.x;
    float s = 0.f;
    #pragma unroll
    for (int j = 0; j < 4; ++j) {
        const int k = lane * 4 + j;
        s += bf2f(h2[r * 256 + k]) * Wout[k];
    }
    #pragma unroll
    for (int off = 32; off > 0; off >>= 1)
        s += __shfl_down(s, off, 64);
    if (lane == 0) {
        const float x = s + bout[0];
        out[r] = 1.f / (1.f + __expf(-x));
    }
}

extern "C" void kernel_launch(void* const* d_in, const int* in_sizes, int n_in,
                              void* d_out, int out_size, void* d_ws, size_t ws_size,
                              hipStream_t stream) {
    const void*  in_mat = d_in[0];                       // f32 512x28000
    const float* adj_sg = (const float*)d_in[1];
    const float* adj_gp = (const float*)d_in[2];
    const float* adj_br = (const float*)d_in[3];
    const float* adj_pp = (const float*)d_in[4];
    const float* W_sg = (const float*)d_in[5];   const float* b_sg = (const float*)d_in[6];
    const float* W_gp = (const float*)d_in[7];   const float* b_gp = (const float*)d_in[8];
    const float* W_br = (const float*)d_in[9];   const float* b_br = (const float*)d_in[10];
    const float* W_pp = (const float*)d_in[11];  const float* b_pp = (const float*)d_in[12];
    const float* W_h1 = (const float*)d_in[13];  const float* b_h1 = (const float*)d_in[14];
    const float* W_h2 = (const float*)d_in[15];  const float* b_h2 = (const float*)d_in[16];
    const float* W_out = (const float*)d_in[17]; const float* b_out = (const float*)d_in[18];

    u16* ws     = (u16*)d_ws;
    u16* bridge = ws;                          // 512 x 8000 bf16
    u16* fuse   = bridge + (size_t)512 * 8000; // 512 x 6000
    u16* h1     = fuse + (size_t)512 * 6000;   // 512 x 1024
    u16* h2     = h1 + (size_t)512 * 1024;     // 512 x 256

    const dim3 blk(256);
    // L1: snp (f32 cols 8000..28000) -> bridge[:, 0:5000]
    masked_gemm_kernel<<<dim3((5000 + 63) / 64, 8), blk, 0, stream>>>(
        in_mat, 28000, 8000, 1, W_sg, adj_sg, b_sg, bridge, 8000, 0, 5000, 20000);
    // L2: gen (f32 cols 3000..8000) -> bridge[:, 5000:8000]
    masked_gemm_kernel<<<dim3((3000 + 63) / 64, 8), blk, 0, stream>>>(
        in_mat, 28000, 3000, 1, W_gp, adj_gp, b_gp, bridge, 8000, 5000, 3000, 5000);
    // L3: bridge (bf16) -> fuse[:, 0:3000]
    masked_gemm_kernel<<<dim3((3000 + 63) / 64, 8), blk, 0, stream>>>(
        bridge, 8000, 0, 0, W_br, adj_br, b_br, fuse, 6000, 0, 3000, 8000);
    // L4: pro (f32 cols 0..3000) -> fuse[:, 3000:6000]
    masked_gemm_kernel<<<dim3((3000 + 63) / 64, 8), blk, 0, stream>>>(
        in_mat, 28000, 0, 1, W_pp, adj_pp, b_pp, fuse, 6000, 3000, 3000, 3000);
    // L5: fuse (bf16) -> h1
    masked_gemm_kernel<<<dim3(1024 / 64, 8), blk, 0, stream>>>(
        fuse, 6000, 0, 0, W_h1, nullptr, b_h1, h1, 1024, 0, 1024, 6000);
    // L6: h1 (bf16) -> h2
    masked_gemm_kernel<<<dim3(256 / 64, 8), blk, 0, stream>>>(
        h1, 1024, 0, 0, W_h2, nullptr, b_h2, h2, 256, 0, 256, 1024);
    // L7: h2 -> out (sigmoid, f32)
    final_kernel<<<dim3(512), dim3(64), 0, stream>>>(h2, W_out, b_out, (float*)d_out);
}